// Round 27
// baseline (629.805 us; speedup 1.0000x reference)
//
#include <hip/hip_runtime.h>
#include <math.h>

// Problem constants
#define Bb 64
#define Nn 1024
#define FDd 768
#define Dd 256
#define KSs 8
#define TSs 12
#define Hh 4
#define HDd 64

typedef __attribute__((ext_vector_type(8))) short bf16x8;
typedef __attribute__((ext_vector_type(4))) float f32x4;

__device__ __forceinline__ ushort f2bf(float x) {
    union { float f; uint u; } v; v.f = x;
    uint r = v.u + 0x7FFFu + ((v.u >> 16) & 1u);   // RNE
    return (ushort)(r >> 16);
}
__device__ __forceinline__ float bf2f(ushort x) {
    union { uint u; float f; } v; v.u = ((uint)x) << 16;
    return v.f;
}
__device__ __forceinline__ uint pack2(float a, float b) {
    return (uint)f2bf(a) | ((uint)f2bf(b) << 16);
}
__device__ __forceinline__ float waveSum(float v) {
    #pragma unroll
    for (int o = 32; o > 0; o >>= 1) v += __shfl_xor(v, o);
    return v;
}
__device__ __forceinline__ float geluf(float v) {
    return 0.5f * v * (1.f + erff(v * 0.70710678118654752f));
}
__device__ __forceinline__ float sigm(float x) { return 1.f / (1.f + expf(-x)); }

// ---- A-fragment loader: 16-row LDS tile, lda in ushorts ----
__device__ __forceinline__ void load_af(bf16x8* af, const ushort* Alds, int lda, int lr, int lk)
{
    #pragma unroll
    for (int c = 0; c < 8; c++)
        af[c] = *(const bf16x8*)(Alds + lr * lda + c * 32 + lk * 8);
}

// ---- pipelined weight-stream matmul, K=256: NT 16-col tiles, depth-2 B prefetch ----
template<int NT, typename F>
__device__ __forceinline__ void mm_stream256(const bf16x8* af,
    const ushort* __restrict__ WT, int n0, int lr, int lk, F&& emit)
{
    const ushort* base = WT + (size_t)(n0 + lr) * 256 + lk * 8;
    bf16x8 bA[8], bB[8], bC[8];
    #pragma unroll
    for (int c = 0; c < 8; c++) bA[c] = *(const bf16x8*)(base + c * 32);
    if (NT > 1) {
        const ushort* nb = base + (size_t)16 * 256;
        #pragma unroll
        for (int c = 0; c < 8; c++) bB[c] = *(const bf16x8*)(nb + c * 32);
    }
    #pragma unroll
    for (int nt = 0; nt < NT; nt++) {
        const bf16x8* bc = (nt % 3 == 0) ? bA : (nt % 3 == 1) ? bB : bC;
        bf16x8* bn = (nt % 3 == 0) ? bC : (nt % 3 == 1) ? bA : bB;
        if (nt + 2 < NT) {
            const ushort* nb = base + (size_t)(nt + 2) * 16 * 256;
            #pragma unroll
            for (int c = 0; c < 8; c++) bn[c] = *(const bf16x8*)(nb + c * 32);
        }
        f32x4 a0 = {0.f, 0.f, 0.f, 0.f}, a1 = {0.f, 0.f, 0.f, 0.f};
        #pragma unroll
        for (int c = 0; c < 8; c += 2) a0 = __builtin_amdgcn_mfma_f32_16x16x32_bf16(af[c], bc[c], a0, 0, 0, 0);
        #pragma unroll
        for (int c = 1; c < 8; c += 2) a1 = __builtin_amdgcn_mfma_f32_16x16x32_bf16(af[c], bc[c], a1, 0, 0, 0);
        emit(nt, a0 + a1);
    }
}

// ---- pipelined matmul K=1024 (A in LDS [16][lda]), NT2 n-tiles, depth-2 prefetch ----
template<int NT2, typename F>
__device__ __forceinline__ void mm_stream_1024(const ushort* Alds, int lda,
    const ushort* __restrict__ WT, int n0, int lr, int lk, F&& emit)
{
    f32x4 acc[NT2] = {};
    bf16x8 bA[8], bB[8], bC[8];
    {
        const ushort* nb = WT + (size_t)(n0 + lr) * 1024 + lk * 8;
        #pragma unroll
        for (int c = 0; c < 8; c++) bA[c] = *(const bf16x8*)(nb + c * 32);
    }
    if (4 * NT2 > 1) {
        const int kc1 = 1 / NT2, nt1 = 1 % NT2;
        const ushort* nb = WT + (size_t)(n0 + nt1 * 16 + lr) * 1024 + kc1 * 256 + lk * 8;
        #pragma unroll
        for (int c = 0; c < 8; c++) bB[c] = *(const bf16x8*)(nb + c * 32);
    }
    #pragma unroll
    for (int kc = 0; kc < 4; kc++) {
        bf16x8 af[8];
        #pragma unroll
        for (int c = 0; c < 8; c++)
            af[c] = *(const bf16x8*)(Alds + lr * lda + kc * 256 + c * 32 + lk * 8);
        #pragma unroll
        for (int nt = 0; nt < NT2; nt++) {
            const int step = kc * NT2 + nt;
            const bf16x8* bc = (step % 3 == 0) ? bA : (step % 3 == 1) ? bB : bC;
            bf16x8* bn = (step % 3 == 0) ? bC : (step % 3 == 1) ? bA : bB;
            if (step + 2 < 4 * NT2) {
                const int kc2 = (step + 2) / NT2, nt2 = (step + 2) % NT2;
                const ushort* nb = WT + (size_t)(n0 + nt2 * 16 + lr) * 1024 + kc2 * 256 + lk * 8;
                #pragma unroll
                for (int c = 0; c < 8; c++) bn[c] = *(const bf16x8*)(nb + c * 32);
            }
            #pragma unroll
            for (int c = 0; c < 8; c++)
                acc[nt] = __builtin_amdgcn_mfma_f32_16x16x32_bf16(af[c], bc[c], acc[nt], 0, 0, 0);
        }
    }
    #pragma unroll
    for (int nt = 0; nt < NT2; nt++) emit(nt, acc[nt]);
}

// LN of a 256-wide f32 LDS row -> bf16 LDS row (one full wave)
__device__ __forceinline__ void ln_row_bf(const float* __restrict__ rowF,
    ushort* __restrict__ rowU, const float* __restrict__ g,
    const float* __restrict__ b, int lane)
{
    float4 x = *(const float4*)&rowF[lane * 4];
    float m = waveSum(x.x + x.y + x.z + x.w) * (1.f / 256.f);
    float d0 = x.x - m, d1 = x.y - m, d2 = x.z - m, d3 = x.w - m;
    float v = waveSum(d0 * d0 + d1 * d1 + d2 * d2 + d3 * d3) * (1.f / 256.f);
    float inv = 1.f / sqrtf(v + 1e-5f);
    float4 gg = *(const float4*)&g[lane * 4];
    float4 bb = *(const float4*)&b[lane * 4];
    ushort4 o;
    o.x = f2bf(d0 * inv * gg.x + bb.x); o.y = f2bf(d1 * inv * gg.y + bb.y);
    o.z = f2bf(d2 * inv * gg.z + bb.z); o.w = f2bf(d3 * inv * gg.w + bb.w);
    *(ushort4*)&rowU[lane * 4] = o;
}

// ============ fused in-proj GEMM + double-LN + k/v projections ============
// Main loop: C64 = features @ in_w (K=768, M-tile 64, 2-barrier reg-staged).
// Epilogue: bias + double-LN -> xS (bf16 LDS, reusing dead staging), then each
// wave weight-streams k_wT/v_wT over its resident 16 xS rows (K=256, seq order
// bit-identical to the standalone k/v GEMM). xnb round-trip eliminated.
#define LPAD 40
__global__ __launch_bounds__(256) void inproj_kv(const float* __restrict__ Ap,
    const ushort* __restrict__ WT,
    const ushort* __restrict__ kwT, const ushort* __restrict__ vwT,
    const float* __restrict__ bias,
    const float* __restrict__ g1, const float* __restrict__ b1,
    const float* __restrict__ g2, const float* __restrict__ b2,
    ushort* __restrict__ kb, ushort* __restrict__ vb)
{
    constexpr int K = 768;
    __shared__ __align__(16) ushort smem[64 * 264];   // staging 12800 < xS 16896
    ushort* As = smem;                    // [64][LPAD]
    ushort* Bs = smem + 64 * LPAD;        // [256][LPAD]
    ushort* xS = smem;                    // [64][264] epilogue (aliases staging)
    const int t = threadIdx.x;
    const int m0 = blockIdx.x * 64;
    const int lane = t & 63, wv = t >> 6;
    const int lr = lane & 15, lk = lane >> 4;

    f32x4 acc[4][4] = {};

    const float*  agf = Ap + (size_t)(m0 + (t >> 2)) * K + (t & 3) * 8;
    const ushort* bg  = WT + (size_t)(t >> 2) * K + (t & 3) * 8;

    float4 fA0, fA1; int4 iB0, iB1, iB2, iB3;

#define GLOAD(k0) do { \
        fA0 = *(const float4*)(agf + (k0)); fA1 = *(const float4*)(agf + (k0) + 4); \
        iB0 = *(const int4*)(bg + (k0)); \
        iB1 = *(const int4*)(bg + (size_t)64  * K + (k0)); \
        iB2 = *(const int4*)(bg + (size_t)128 * K + (k0)); \
        iB3 = *(const int4*)(bg + (size_t)192 * K + (k0)); \
    } while (0)

#define LSTORE() do { \
        int4 w; \
        w.x = pack2(fA0.x, fA0.y); w.y = pack2(fA0.z, fA0.w); \
        w.z = pack2(fA1.x, fA1.y); w.w = pack2(fA1.z, fA1.w); \
        *(int4*)&As[(t >> 2) * LPAD + (t & 3) * 8] = w; \
        *(int4*)&Bs[(t >> 2) * LPAD + (t & 3) * 8]         = iB0; \
        *(int4*)&Bs[(64 + (t >> 2)) * LPAD + (t & 3) * 8]  = iB1; \
        *(int4*)&Bs[(128 + (t >> 2)) * LPAD + (t & 3) * 8] = iB2; \
        *(int4*)&Bs[(192 + (t >> 2)) * LPAD + (t & 3) * 8] = iB3; \
    } while (0)

    GLOAD(0);
    for (int k0 = 0; k0 < K; k0 += 32) {
        LSTORE();
        __syncthreads();
        bf16x8 af[4], bfr[4];
        #pragma unroll
        for (int mi = 0; mi < 4; mi++)
            af[mi] = *(const bf16x8*)&As[(mi * 16 + lr) * LPAD + lk * 8];
        #pragma unroll
        for (int ni = 0; ni < 4; ni++)
            bfr[ni] = *(const bf16x8*)&Bs[(wv * 64 + ni * 16 + lr) * LPAD + lk * 8];
        if (k0 + 32 < K) GLOAD(k0 + 32);
        #pragma unroll
        for (int mi = 0; mi < 4; mi++)
            #pragma unroll
            for (int ni = 0; ni < 4; ni++)
                acc[mi][ni] = __builtin_amdgcn_mfma_f32_16x16x32_bf16(af[mi], bfr[ni], acc[mi][ni], 0, 0, 0);
        __syncthreads();
    }
#undef GLOAD
#undef LSTORE
    // bias + bf16 -> xS (staging LDS is dead; last loop iteration ended with barrier)
    #pragma unroll
    for (int mi = 0; mi < 4; mi++) {
        int row = mi * 16 + lk * 4;
        #pragma unroll
        for (int ni = 0; ni < 4; ni++) {
            int col = wv * 64 + ni * 16 + lr;
            float bv = bias[col];
            #pragma unroll
            for (int r = 0; r < 4; r++)
                xS[(row + r) * 264 + col] = f2bf(acc[mi][ni][r] + bv);
        }
    }
    __syncthreads();
    // double-LN in place: wave wv handles rows wv*16 .. wv*16+15
    #pragma unroll
    for (int rr = 0; rr < 16; rr++) {
        int row = wv * 16 + rr;
        ushort4 u = *(const ushort4*)&xS[row * 264 + lane * 4];
        float x0 = bf2f(u.x), x1 = bf2f(u.y), x2 = bf2f(u.z), x3 = bf2f(u.w);
        float m = waveSum(x0 + x1 + x2 + x3) * (1.f / 256.f);
        float d0 = x0 - m, d1 = x1 - m, d2 = x2 - m, d3 = x3 - m;
        float v = waveSum(d0 * d0 + d1 * d1 + d2 * d2 + d3 * d3) * (1.f / 256.f);
        float inv = 1.f / sqrtf(v + 1e-5f);
        float4 gg = *(const float4*)&g1[lane * 4];
        float4 bbv = *(const float4*)&b1[lane * 4];
        float y0 = d0 * inv * gg.x + bbv.x, y1 = d1 * inv * gg.y + bbv.y;
        float y2 = d2 * inv * gg.z + bbv.z, y3 = d3 * inv * gg.w + bbv.w;
        float m2 = waveSum(y0 + y1 + y2 + y3) * (1.f / 256.f);
        float e0 = y0 - m2, e1 = y1 - m2, e2 = y2 - m2, e3 = y3 - m2;
        float v2 = waveSum(e0 * e0 + e1 * e1 + e2 * e2 + e3 * e3) * (1.f / 256.f);
        float inv2 = 1.f / sqrtf(v2 + 1e-5f);
        float4 g2v = *(const float4*)&g2[lane * 4];
        float4 b2v = *(const float4*)&b2[lane * 4];
        ushort4 o;
        o.x = f2bf(e0 * inv2 * g2v.x + b2v.x); o.y = f2bf(e1 * inv2 * g2v.y + b2v.y);
        o.z = f2bf(e2 * inv2 * g2v.z + b2v.z); o.w = f2bf(e3 * inv2 * g2v.w + b2v.w);
        *(ushort4*)&xS[row * 264 + lane * 4] = o;
    }
    __syncthreads();
    // k/v projections: each wave streams both weight matrices over its 16 xS rows.
    // Sequential-c accumulation == standalone K-step order (bit-identical).
    bf16x8 af2[8];
    load_af(af2, xS + (wv * 16) * 264, 264, lr, lk);
    #pragma unroll
    for (int wsel = 0; wsel < 2; wsel++) {
        const ushort* W = wsel ? vwT : kwT;
        ushort* outp = wsel ? vb : kb;
        bf16x8 bufA[8], bufB[8];
        {
            const ushort* nb = W + (size_t)lr * 256 + lk * 8;
            #pragma unroll
            for (int c = 0; c < 8; c++) bufA[c] = *(const bf16x8*)(nb + c * 32);
        }
        #pragma unroll
        for (int nt = 0; nt < 16; nt++) {
            const bf16x8* cur = (nt & 1) ? bufB : bufA;
            bf16x8* nxt = (nt & 1) ? bufA : bufB;
            if (nt + 1 < 16) {
                const ushort* nb = W + (size_t)((nt + 1) * 16 + lr) * 256 + lk * 8;
                #pragma unroll
                for (int c = 0; c < 8; c++) nxt[c] = *(const bf16x8*)(nb + c * 32);
            }
            f32x4 a = {0.f, 0.f, 0.f, 0.f};
            #pragma unroll
            for (int c = 0; c < 8; c++)
                a = __builtin_amdgcn_mfma_f32_16x16x32_bf16(af2[c], cur[c], a, 0, 0, 0);
            int n = nt * 16 + lr;
            #pragma unroll
            for (int r = 0; r < 4; r++)
                outp[(size_t)(m0 + wv * 16 + lk * 4 + r) * 256 + n] = f2bf(a[r]);
        }
    }
}

// ---------------- tiled transpose+cast for all 14 weight matrices ----------------
struct PrepArgsT {
    const float* src[14];
    ushort* dst[14];
    int K[14];
    int N[14];
    int tstart[15];
};
__global__ __launch_bounds__(256) void prep_tiled(PrepArgsT pa)
{
    __shared__ float s[32][33];
    int tile = blockIdx.x;
    int seg = 0;
    while (tile >= pa.tstart[seg + 1]) seg++;
    int lt = tile - pa.tstart[seg];
    int K = pa.K[seg], N = pa.N[seg];
    int tpr = N >> 5;
    int k0 = (lt / tpr) << 5, n0 = (lt % tpr) << 5;
    const float* src = pa.src[seg];
    ushort* dst = pa.dst[seg];
    int r = threadIdx.x >> 5, c = threadIdx.x & 31;
    #pragma unroll
    for (int rr = 0; rr < 32; rr += 8)
        s[rr + r][c] = src[(size_t)(k0 + rr + r) * N + n0 + c];
    __syncthreads();
    #pragma unroll
    for (int rr = 0; rr < 32; rr += 8)
        dst[(size_t)(n0 + rr + r) * K + k0 + c] = f2bf(s[c][rr + r]);
}

// ---------------- slots init + LN + q (per batch, 8 waves) ----------------
__global__ __launch_bounds__(512) void slot_init_q(
    const float* __restrict__ mu, const float* __restrict__ ls,
    const float* __restrict__ eps, float* __restrict__ slots_g,
    float* __restrict__ qbuf, const ushort* __restrict__ qwT,
    const float* __restrict__ ns_g, const float* __restrict__ ns_b)
{
    __shared__ float sF[16 * 256];
    __shared__ __align__(16) ushort sU[16 * 264];
    int b = blockIdx.x, t = threadIdx.x;
    int lane = t & 63, wv = t >> 6, lr = lane & 15, lk = lane >> 4;
    for (int idx = t; idx < 4096; idx += 512) {
        int i = idx >> 8, c = idx & 255;
        float v = 0.f;
        if (i < 12) {
            int md = i * 256 + c;
            v = mu[md] + expf(ls[md]) * eps[(size_t)(b * 12 + i) * 256 + c];
            slots_g[(size_t)(b * 12 + i) * 256 + c] = v;
        }
        sF[idx] = v;
        sU[i * 264 + c] = 0;
    }
    __syncthreads();
    ln_row_bf(sF + wv * 256, sU + wv * 264, ns_g, ns_b, lane);
    if (wv < 4) ln_row_bf(sF + (8 + wv) * 256, sU + (8 + wv) * 264, ns_g, ns_b, lane);
    __syncthreads();
    bf16x8 af[8];
    load_af(af, sU, 264, lr, lk);
    mm_stream256<2>(af, qwT, wv * 32, lr, lk, [&](int nt, f32x4 a) {
        int n = wv * 32 + nt * 16 + lr;
        #pragma unroll
        for (int r = 0; r < 4; r++) {
            int m = lk * 4 + r;
            if (m < 12) qbuf[(size_t)(b * 12 + m) * 256 + n] = a[r] * 0.125f;
        }
    });
}

// ---------------- fused dots + softmax48 (attn stored bf16) ----------------
__global__ __launch_bounds__(256) void dots_softmax(const float* __restrict__ qb,
    const ushort* __restrict__ kb, ushort* __restrict__ attnb)
{
    int b = blockIdx.x >> 2, chunk = blockIdx.x & 3;
    int t = threadIdx.x;
    int j = chunk * 256 + t;
    const float* qbase = qb + (size_t)b * 12 * 256;
    float a48[48];
    #pragma unroll
    for (int h = 0; h < 4; h++) {
        const uint* kp = (const uint*)(kb + (size_t)(b * Nn + j) * 256 + h * 64);
        float kr[64];
        #pragma unroll
        for (int c = 0; c < 8; c++) {
            int4 k4 = *(const int4*)(kp + c * 4);
            uint u0 = (uint)k4.x, u1 = (uint)k4.y, u2 = (uint)k4.z, u3 = (uint)k4.w;
            kr[c * 8 + 0] = __uint_as_float(u0 << 16); kr[c * 8 + 1] = __uint_as_float(u0 & 0xffff0000u);
            kr[c * 8 + 2] = __uint_as_float(u1 << 16); kr[c * 8 + 3] = __uint_as_float(u1 & 0xffff0000u);
            kr[c * 8 + 4] = __uint_as_float(u2 << 16); kr[c * 8 + 5] = __uint_as_float(u2 & 0xffff0000u);
            kr[c * 8 + 6] = __uint_as_float(u3 << 16); kr[c * 8 + 7] = __uint_as_float(u3 & 0xffff0000u);
        }
        #pragma unroll
        for (int i = 0; i < 12; i++) {
            const float* qr = qbase + i * 256 + h * 64;
            float acc = 0.f;
            #pragma unroll
            for (int c = 0; c < 64; c++) acc += kr[c] * qr[c];
            a48[i * 4 + h] = acc;
        }
    }
    float m = -1e30f;
    #pragma unroll
    for (int idx = 0; idx < 48; idx++) m = fmaxf(m, a48[idx]);
    float s = 0.f;
    #pragma unroll
    for (int idx = 0; idx < 48; idx++) { a48[idx] = expf(a48[idx] - m); s += a48[idx]; }
    float inv = 1.f / s;
    #pragma unroll
    for (int idx = 0; idx < 48; idx++)
        attnb[(size_t)(b * 48 + idx) * Nn + j] = f2bf(a48[idx] * inv);
}

// ---------------- updates with fused rowsum; bf16x8 (16B) v-loads ----------------
__global__ __launch_bounds__(512) void updates_kernel(const ushort* __restrict__ attnb,
    const ushort* __restrict__ vb, float* __restrict__ upd)
{
    int b = blockIdx.x >> 2, h = blockIdx.x & 3;
    int t = threadIdx.x, w = t >> 6, lane = t & 63;
    int jj = lane >> 3, dg = lane & 7;
    float acc[12][8] = {};
    float ra[12] = {};
    float accv[8] = {};
    for (int jb = w * 8; jb < Nn; jb += 64) {
        int j = jb + jj;
        bf16x8 v8 = *(const bf16x8*)&vb[(size_t)(b * Nn + j) * Dd + h * HDd + dg * 8];
        float vv[8];
        #pragma unroll
        for (int r = 0; r < 8; r++) { vv[r] = bf2f((ushort)v8[r]); accv[r] += vv[r]; }
        #pragma unroll
        for (int i = 0; i < 12; i++) {
            float a = bf2f(attnb[(size_t)(b * 48 + i * 4 + h) * Nn + j]);
            #pragma unroll
            for (int r = 0; r < 8; r++) acc[i][r] += a * vv[r];
            ra[i] += a;
        }
    }
    #pragma unroll
    for (int i = 0; i < 12; i++) {
        #pragma unroll
        for (int r = 0; r < 8; r++) {
            acc[i][r] += __shfl_xor(acc[i][r], 8);
            acc[i][r] += __shfl_xor(acc[i][r], 16);
            acc[i][r] += __shfl_xor(acc[i][r], 32);
        }
        ra[i] += __shfl_xor(ra[i], 8);
        ra[i] += __shfl_xor(ra[i], 16);
        ra[i] += __shfl_xor(ra[i], 32);
    }
    #pragma unroll
    for (int r = 0; r < 8; r++) {
        accv[r] += __shfl_xor(accv[r], 8);
        accv[r] += __shfl_xor(accv[r], 16);
        accv[r] += __shfl_xor(accv[r], 32);
    }
    __shared__ float redA[8][12][64];
    __shared__ float redV[8][64];
    __shared__ float redR[8][12];
    if (lane < 8) {
        #pragma unroll
        for (int i = 0; i < 12; i++)
            #pragma unroll
            for (int r = 0; r < 8; r++)
                redA[w][i][lane * 8 + r] = acc[i][r];
        #pragma unroll
        for (int r = 0; r < 8; r++) redV[w][lane * 8 + r] = accv[r];
        if (lane == 0) {
            #pragma unroll
            for (int i = 0; i < 12; i++) redR[w][i] = ra[i];
        }
    }
    __syncthreads();
    if (w == 0) {
        float sv = 0.f;
        #pragma unroll
        for (int ww = 0; ww < 8; ww++) sv += redV[ww][lane];
        #pragma unroll
        for (int i = 0; i < 12; i++) {
            float s = 0.f, rs = 0.f;
            #pragma unroll
            for (int ww = 0; ww < 8; ww++) { s += redA[ww][i][lane]; rs += redR[ww][i]; }
            upd[(size_t)(b * TSs + i) * Dd + h * HDd + lane] = (s + 1e-8f * sv) / (rs + 1e-8f);
        }
    }
}

// ---------------- GRU matmuls, column-parallel: grid (64 batches, 4 quarters) ----------------
__global__ __launch_bounds__(256) void gru_mm(const float* __restrict__ upd,
    const float* __restrict__ slots_g,
    const ushort* __restrict__ wihT, const ushort* __restrict__ whhT,
    const float* __restrict__ bih, const float* __restrict__ bhh,
    float* __restrict__ gxh)
{
    __shared__ __align__(16) ushort sU[16 * 264], sS[16 * 264];
    int b = blockIdx.x, q = blockIdx.y, t = threadIdx.x;
    int lane = t & 63, wv = t >> 6, lr = lane & 15, lk = lane >> 4;
    for (int idx = t; idx < 4096; idx += 256) {
        int i = idx >> 8, c = idx & 255;
        float uv = 0.f, sv = 0.f;
        if (i < 12) {
            uv = upd[(size_t)(b * 12 + i) * 256 + c];
            sv = slots_g[(size_t)(b * 12 + i) * 256 + c];
        }
        sU[i * 264 + c] = f2bf(uv);
        sS[i * 264 + c] = f2bf(sv);
    }
    __syncthreads();
    bool ih = (wv < 2);
    bf16x8 af[8];
    load_af(af, ih ? sU : sS, 264, lr, lk);
    const ushort* W = ih ? wihT : whhT;
    const float* bias = ih ? bih : bhh;
    float* outp = gxh + (size_t)(b * 2 + (ih ? 0 : 1)) * 12 * 768;
    int n0 = q * 192 + (wv & 1) * 96;
    mm_stream256<6>(af, W, n0, lr, lk, [&](int nt, f32x4 a) {
        int n = n0 + nt * 16 + lr;
        float bv = bias[n];
        #pragma unroll
        for (int r = 0; r < 4; r++) {
            int m = lk * 4 + r;
            if (m < 12) outp[m * 768 + n] = a[r] + bv;
        }
    });
}

// ---------------- gate + FFN-LN + FFN1 quarter: grid (64, 4) ----------------
__global__ __launch_bounds__(256) void gate_ffn1(const float* __restrict__ gxh,
    const float* __restrict__ slots_g, float* __restrict__ slots2,
    const ushort* __restrict__ fw1T,
    const float* __restrict__ fln_g, const float* __restrict__ fln_b,
    const float* __restrict__ f_b1, ushort* __restrict__ h1b)
{
    __shared__ float sF[12 * 256];
    __shared__ __align__(16) ushort sU[16 * 264];
    int b = blockIdx.x, q = blockIdx.y, t = threadIdx.x;
    int lane = t & 63, wv = t >> 6, lr = lane & 15, lk = lane >> 4;
    for (int idx = t; idx < 1056; idx += 256) sU[12 * 264 + idx] = 0;
    for (int idx = t; idx < 3072; idx += 256) {
        int i = idx >> 8, c = idx & 255;
        const float* gx = gxh + (size_t)(b * 2) * 12 * 768 + i * 768;
        const float* gh = gxh + (size_t)(b * 2 + 1) * 12 * 768 + i * 768;
        float r = sigm(gx[c] + gh[c]);
        float z = sigm(gx[256 + c] + gh[256 + c]);
        float nv = tanhf(gx[512 + c] + r * gh[512 + c]);
        float hp = slots_g[(size_t)(b * 12 + i) * 256 + c];
        float out = (1.f - z) * nv + z * hp;
        sF[idx] = out;
        if (q == 0) slots2[(size_t)(b * 12 + i) * 256 + c] = out;
    }
    __syncthreads();
    for (int rr = 0; rr < 3; rr++) {
        int row = wv * 3 + rr;
        ln_row_bf(sF + row * 256, sU + row * 264, fln_g, fln_b, lane);
    }
    __syncthreads();
    bf16x8 af[8];
    load_af(af, sU, 264, lr, lk);
    int n0 = q * 256 + wv * 64;
    mm_stream256<4>(af, fw1T, n0, lr, lk, [&](int nt, f32x4 a) {
        int n = n0 + nt * 16 + lr;
        float bv = f_b1[n];
        #pragma unroll
        for (int r = 0; r < 4; r++) {
            int m = lk * 4 + r;
            if (m < 12) h1b[(size_t)(b * 12 + m) * 1024 + n] = f2bf(geluf(a[r] + bv));
        }
    });
}

// ---------------- FFN2 matmul + residual, column-quarter: grid (64, 4) ----------------
__global__ __launch_bounds__(256) void ffn2_mm(const ushort* __restrict__ h1b,
    const float* __restrict__ slots2, float* __restrict__ slots_g,
    const ushort* __restrict__ fw2T, const float* __restrict__ f_b2)
{
    __shared__ __align__(16) ushort hS[16 * 1032];
    int b = blockIdx.x, q = blockIdx.y, t = threadIdx.x;
    int lane = t & 63, wv = t >> 6, lr = lane & 15, lk = lane >> 4;
    for (int ch = t; ch < 2048; ch += 256) {
        int i = ch >> 7, c8 = (ch & 127) * 8;
        int4 v = {0, 0, 0, 0};
        if (i < 12) v = *(const int4*)&h1b[(size_t)(b * 12 + i) * 1024 + c8];
        *(int4*)&hS[i * 1032 + c8] = v;
    }
    __syncthreads();
    int n0 = q * 64 + wv * 16;
    mm_stream_1024<1>(hS, 1032, fw2T, n0, lr, lk, [&](int nt, f32x4 a) {
        (void)nt;
        int n = n0 + lr;
        float bv = f_b2[n];
        #pragma unroll
        for (int r = 0; r < 4; r++) {
            int m = lk * 4 + r;
            if (m < 12)
                slots_g[(size_t)(b * 12 + m) * 256 + n] =
                    a[r] + bv + slots2[(size_t)(b * 12 + m) * 256 + n];
        }
    });
}

// ---------------- LN(slots) + q projection: grid 64, 8 waves (it < 2 only) ----------------
__global__ __launch_bounds__(512) void ln_q(const float* __restrict__ slots_g,
    float* __restrict__ qbuf, const ushort* __restrict__ qwT,
    const float* __restrict__ ns_g, const float* __restrict__ ns_b)
{
    __shared__ float sF[12 * 256];
    __shared__ __align__(16) ushort sU[16 * 264];
    int b = blockIdx.x, t = threadIdx.x;
    int lane = t & 63, wv = t >> 6, lr = lane & 15, lk = lane >> 4;
    for (int idx = t; idx < 3072; idx += 512) sF[idx] = slots_g[(size_t)b * 3072 + idx];
    for (int idx = t; idx < 1056; idx += 512) sU[12 * 264 + idx] = 0;
    __syncthreads();
    ln_row_bf(sF + wv * 256, sU + wv * 264, ns_g, ns_b, lane);
    if (wv < 4) ln_row_bf(sF + (8 + wv) * 256, sU + (8 + wv) * 264, ns_g, ns_b, lane);
    __syncthreads();
    bf16x8 af[8];
    load_af(af, sU, 264, lr, lk);
    mm_stream256<2>(af, qwT, wv * 32, lr, lk, [&](int nt, f32x4 a) {
        int n = wv * 32 + nt * 16 + lr;
        #pragma unroll
        for (int r = 0; r < 4; r++) {
            int m = lk * 4 + r;
            if (m < 12) qbuf[(size_t)(b * 12 + m) * 256 + n] = a[r] * 0.125f;
        }
    });
}

// ---------------- selection head + masked x write ----------------
__global__ __launch_bounds__(256) void select_kernel(const float* __restrict__ slots,
    const float* __restrict__ w1, const float* __restrict__ b1,
    const float* __restrict__ w2, const float* __restrict__ b2,
    float* __restrict__ dec, float* __restrict__ xout)
{
    int b = blockIdx.x, t = threadIdx.x;
    __shared__ float t1[8][128];
    __shared__ float lg[8][2];
    __shared__ float dsh[8];
    const float* obj = slots + (size_t)b * TSs * Dd;
    #pragma unroll
    for (int u = 0; u < 4; u++) {
        int idx = t + 256 * u;
        int k = idx >> 7, c = idx & 127;
        float s = b1[c];
        for (int d = 0; d < 256; d++) s += obj[k * 256 + d] * w1[d * 128 + c];
        t1[k][c] = fmaxf(s, 0.f);
    }
    __syncthreads();
    if (t < 16) {
        int k = t >> 1, o = t & 1;
        float s = b2[o];
        for (int c = 0; c < 128; c++) s += t1[k][c] * w2[c * 2 + o];
        lg[k][o] = s;
    }
    __syncthreads();
    if (t == 0) {
        float dv[8]; float sum = 0.f;
        for (int k = 0; k < 8; k++) { dv[k] = (lg[k][1] > lg[k][0]) ? 1.f : 0.f; sum += dv[k]; }
        float needed = fmaxf(2.f - sum, 0.f);
        float rank = 0.f;
        for (int k = 0; k < 8; k++) {
            float inact = 1.f - dv[k];
            rank += inact;
            if (inact > 0.f && rank <= needed) dv[k] = 1.f;
            dsh[k] = dv[k];
            dec[b * 8 + k] = dv[k];
        }
    }
    __syncthreads();
    for (int idx = t; idx < 2048; idx += 256) {
        int k = idx >> 8, c = idx & 255;
        xout[(size_t)(b * 8 + k) * 256 + c] = obj[k * 256 + c] * dsh[k];
    }
}

// ---------------- GAT: LN + proj + attention + residual + post-LN: grid 64 ----------------
__global__ __launch_bounds__(256) void gat_attn(const float* __restrict__ xin,
    const float* __restrict__ dec, const ushort* __restrict__ gWT,
    const float* __restrict__ av,
    const float* __restrict__ lng, const float* __restrict__ lnb,
    const float* __restrict__ flng, const float* __restrict__ flnb,
    float* __restrict__ yF, ushort* __restrict__ ylnb)
{
    __shared__ float xF[8 * 256];
    __shared__ float hmF[8 * 256];
    __shared__ __align__(16) ushort sU[16 * 264];
    __shared__ float ei[8][4], ej[8][4], al[8][4][8], ds[8];
    int b = blockIdx.x, t = threadIdx.x;
    int lane = t & 63, wv = t >> 6, lr = lane & 15, lk = lane >> 4;

    for (int idx = t; idx < 2048; idx += 256) xF[idx] = xin[(size_t)b * 2048 + idx];
    for (int idx = t; idx < 2112; idx += 256) sU[8 * 264 + idx] = 0;
    if (t < 8) ds[t] = dec[b * 8 + t];
    __syncthreads();
    ln_row_bf(xF + (wv * 2) * 256, sU + (wv * 2) * 264, lng, lnb, lane);
    ln_row_bf(xF + (wv * 2 + 1) * 256, sU + (wv * 2 + 1) * 264, lng, lnb, lane);
    __syncthreads();
    {
        bf16x8 af[8];
        load_af(af, sU, 264, lr, lk);
        mm_stream256<4>(af, gWT, wv * 64, lr, lk, [&](int nt, f32x4 a) {
            int n = wv * 64 + nt * 16 + lr;
            #pragma unroll
            for (int r = 0; r < 4; r++) {
                int m = lk * 4 + r;
                if (m < 8) hmF[m * 256 + n] = a[r];
            }
        });
    }
    __syncthreads();
    {
        int pair = t >> 3, sub = t & 7;
        int k = pair >> 2, h = pair & 3;
        const float* hrow = hmF + k * 256 + h * 64 + sub * 8;
        float s1 = 0.f, s2 = 0.f;
        #pragma unroll
        for (int d = 0; d < 8; d++) {
            float hv = hrow[d];
            s1 += hv * av[h * 128 + sub * 8 + d];
            s2 += hv * av[h * 128 + 64 + sub * 8 + d];
        }
        #pragma unroll
        for (int o = 1; o < 8; o <<= 1) { s1 += __shfl_xor(s1, o); s2 += __shfl_xor(s2, o); }
        if (sub == 0) { ei[k][h] = s1; ej[k][h] = s2; }
    }
    __syncthreads();
    {
        int k = t >> 5, h = (t >> 3) & 3, n = t & 7;
        float e = ei[k][h] + ej[n][h];
        e = (e >= 0.f) ? e : 0.2f * e;
        if (ds[k] * ds[n] == 0.f) e = -1e9f;
        float mx = e;
        #pragma unroll
        for (int o = 4; o > 0; o >>= 1) mx = fmaxf(mx, __shfl_xor(mx, o, 8));
        float ex = expf(e - mx);
        float sm = ex;
        #pragma unroll
        for (int o = 4; o > 0; o >>= 1) sm += __shfl_xor(sm, o, 8);
        al[k][h][n] = ex / sm;
    }
    __syncthreads();
    {
        int h = t >> 6, d = t & 63;
        #pragma unroll
        for (int k = 0; k < 8; k++) {
            float o = 0.f;
            #pragma unroll
            for (int n = 0; n < 8; n++) o += al[k][h][n] * hmF[n * 256 + h * 64 + d];
            xF[k * 256 + h * 64 + d] += o;
        }
    }
    __syncthreads();
    for (int idx = t; idx < 2048; idx += 256) yF[(size_t)b * 2048 + idx] = xF[idx];
    ln_row_bf(xF + (wv * 2) * 256, sU + (wv * 2) * 264, flng, flnb, lane);
    ln_row_bf(xF + (wv * 2 + 1) * 256, sU + (wv * 2 + 1) * 264, flng, flnb, lane);
    __syncthreads();
    for (int idx = t; idx < 2048; idx += 256) {
        int i = idx >> 8, c = idx & 255;
        ylnb[(size_t)b * 2048 + idx] = sU[i * 264 + c];
    }
}

// ---------------- GAT FFN1 quarter: grid (64, 4) ----------------
__global__ __launch_bounds__(256) void gat_ffn1(const ushort* __restrict__ ylnb,
    const ushort* __restrict__ g1T, const float* __restrict__ fb1,
    ushort* __restrict__ gh1)
{
    __shared__ __align__(16) ushort sU[16 * 264];
    int b = blockIdx.x, q = blockIdx.y, t = threadIdx.x;
    int lane = t & 63, wv = t >> 6, lr = lane & 15, lk = lane >> 4;
    for (int idx = t; idx < 4096; idx += 256) {
        int i = idx >> 8, c = idx & 255;
        sU[i * 264 + c] = (i < 8) ? ylnb[(size_t)b * 2048 + i * 256 + c] : 0;
    }
    __syncthreads();
    bf16x8 af[8];
    load_af(af, sU, 264, lr, lk);
    int n0 = q * 256 + wv * 64;
    mm_stream256<4>(af, g1T, n0, lr, lk, [&](int nt, f32x4 a) {
        int n = n0 + nt * 16 + lr;
        float bv = fb1[n];
        #pragma unroll
        for (int r = 0; r < 4; r++) {
            int m = lk * 4 + r;
            if (m < 8) gh1[(size_t)(b * 8 + m) * 1024 + n] = f2bf(geluf(a[r] + bv));
        }
    });
}

// ---------------- GAT FFN2 + residual: grid (64, 4), 64-col slices ----------------
__global__ __launch_bounds__(256) void gat_ffn2(const ushort* __restrict__ gh1,
    const float* __restrict__ yF, const ushort* __restrict__ g2T,
    const float* __restrict__ fb2, float* __restrict__ out)
{
    __shared__ __align__(16) ushort hS[16 * 1032];
    int b = blockIdx.x, q = blockIdx.y, t = threadIdx.x;
    int lane = t & 63, wv = t >> 6, lr = lane & 15, lk = lane >> 4;
    for (int ch = t; ch < 2048; ch += 256) {
        int i = ch >> 7, c8 = (ch & 127) * 8;
        int4 v = {0, 0, 0, 0};
        if (i < 8) v = *(const int4*)&gh1[(size_t)(b * 8 + i) * 1024 + c8];
        *(int4*)&hS[i * 1032 + c8] = v;
    }
    __syncthreads();
    int n0 = q * 64 + wv * 16;
    mm_stream_1024<1>(hS, 1032, g2T, n0, lr, lk, [&](int nt, f32x4 a) {
        (void)nt;
        int n = n0 + lr;
        float bv = fb2[n];
        #pragma unroll
        for (int r = 0; r < 4; r++) {
            int m = lk * 4 + r;
            if (m < 8) out[(size_t)(b * 8 + m) * 256 + n] = a[r] + bv + yF[(size_t)(b * 8 + m) * 256 + n];
        }
    });
}

// ======================================================================
extern "C" void kernel_launch(void* const* d_in, const int* in_sizes, int n_in,
                              void* d_out, int out_size, void* d_ws, size_t ws_size,
                              hipStream_t stream)
{
    (void)in_sizes; (void)n_in; (void)out_size; (void)ws_size;
    const float* features       = (const float*)d_in[0];
    const float* eps_noise      = (const float*)d_in[1];
    const float* in_w           = (const float*)d_in[2];
    const float* in_b           = (const float*)d_in[3];
    const float* in_ln_g        = (const float*)d_in[4];
    const float* in_ln_b        = (const float*)d_in[5];
    const float* ni_g           = (const float*)d_in[6];
    const float* ni_b           = (const float*)d_in[7];
    const float* slot_mu        = (const float*)d_in[8];
    const float* slot_log_sigma = (const float*)d_in[9];
    const float* q_w            = (const float*)d_in[10];
    const float* k_w            = (const float*)d_in[11];
    const float* v_w            = (const float*)d_in[12];
    const float* gru_wih        = (const float*)d_in[13];
    const float* gru_whh        = (const float*)d_in[14];
    const float* gru_bih        = (const float*)d_in[15];
    const float* gru_bhh        = (const float*)d_in[16];
    const float* ns_g           = (const float*)d_in[17];
    const float* ns_b           = (const float*)d_in[18];
    const float* ffn_ln_g       = (const float*)d_in[19];
    const float* ffn_ln_b       = (const float*)d_in[20];
    const float* ffn_w1         = (const float*)d_in[21];
    const float* ffn_b1         = (const float*)d_in[22];
    const float* ffn_w2         = (const float*)d_in[23];
    const float* ffn_b2         = (const float*)d_in[24];
    const float* sel_w1         = (const float*)d_in[25];
    const float* sel_b1         = (const float*)d_in[26];
    const float* sel_w2         = (const float*)d_in[27];
    const float* sel_b2         = (const float*)d_in[28];
    const float* gat_W          = (const float*)d_in[29];
    const float* gat_a          = (const float*)d_in[30];
    const float* gat_ln_g       = (const float*)d_in[31];
    const float* gat_ln_b       = (const float*)d_in[32];
    const float* gat_fln_g      = (const float*)d_in[33];
    const float* gat_fln_b      = (const float*)d_in[34];
    const float* gat_fw1        = (const float*)d_in[35];
    const float* gat_fb1        = (const float*)d_in[36];
    const float* gat_fw2        = (const float*)d_in[37];
    const float* gat_fb2        = (const float*)d_in[38];

    // ---- workspace layout ----
    ushort* kb  = (ushort*)d_ws;
    ushort* vb  = kb + 16777216;
    ushort* xnb = vb + 16777216;          // unused (kv fused into in-proj)
    ushort* wtb = xnb + 16777216;         // 2,490,368 transposed bf16 weights
    ushort* h1b  = wtb + 2490368;         // 786,432
    ushort* ylnb = h1b + 786432;          // 131,072
    ushort* gh1  = ylnb + 131072;         // 524,288
    ushort* attnb = gh1 + 524288;         // 3,145,728 bf16 attn
    float* fbase = (float*)(attnb + 3145728);
    float* slots  = fbase;                // 196,608
    float* slots2 = slots + 196608;       // 196,608
    float* qbuf   = slots2 + 196608;      // 196,608
    float* upd    = qbuf + 196608;        // 196,608
    float* gxh    = upd + 196608;         // 1,179,648
    float* xb     = gxh + 1179648;        // 131,072
    float* yF     = xb + 131072;          // 131,072
    float* dec    = yF + 131072;          // 512

    ushort* in_wT = wtb;                  // 196608
    ushort* k_wT  = in_wT + 196608;       // 65536
    ushort* v_wT  = k_wT + 65536;
    ushort* q_wT  = v_wT + 65536;
    ushort* wihT  = q_wT + 65536;         // 196608
    ushort* whhT  = wihT + 196608;
    ushort* fw1T  = whhT + 196608;        // 262144
    ushort* fw2T  = fw1T + 262144;
    ushort* gW0T  = fw2T + 262144;        // 65536
    ushort* gW1T  = gW0T + 65536;
    ushort* gf1aT = gW1T + 65536;         // 262144
    ushort* gf1bT = gf1aT + 262144;
    ushort* gf2aT = gf1bT + 262144;
    ushort* gf2bT = gf2aT + 262144;

    dim3 blk(256);

    // 0) all weights -> bf16 [N][K], 32x32 LDS-tiled
    PrepArgsT pa;
    const float* srcs[14] = { in_w, k_w, v_w, q_w, gru_wih, gru_whh, ffn_w1, ffn_w2,
                              gat_W, gat_W + 65536, gat_fw1, gat_fw1 + 262144,
                              gat_fw2, gat_fw2 + 262144 };
    ushort* dsts[14] = { in_wT, k_wT, v_wT, q_wT, wihT, whhT, fw1T, fw2T,
                         gW0T, gW1T, gf1aT, gf1bT, gf2aT, gf2bT };
    int Ks[14]  = { 768, 256, 256, 256, 256, 256, 256, 1024, 256, 256, 256, 256, 1024, 1024 };
    int Nsz[14] = { 256, 256, 256, 256, 768, 768, 1024, 256, 256, 256, 1024, 1024, 256, 256 };
    int tcum = 0;
    for (int s = 0; s < 14; s++) {
        pa.src[s] = srcs[s]; pa.dst[s] = dsts[s]; pa.K[s] = Ks[s]; pa.N[s] = Nsz[s];
        pa.tstart[s] = tcum;
        tcum += (Ks[s] >> 5) * (Nsz[s] >> 5);
    }
    pa.tstart[14] = tcum;
    prep_tiled<<<tcum, blk, 0, stream>>>(pa);

    // 1) fused: xn = LN(LN(features @ in_w + in_b)); k,v = xn @ {k_w,v_w} (no xnb)
    inproj_kv<<<1024, blk, 0, stream>>>(features, in_wT, k_wT, v_wT, in_b,
                                        in_ln_g, in_ln_b, ni_g, ni_b, kb, vb);

    // 2) slots init + first q
    slot_init_q<<<Bb, dim3(512), 0, stream>>>(slot_mu, slot_log_sigma, eps_noise,
                                              slots, qbuf, q_wT, ns_g, ns_b);

    // 3) slot-attention iterations (column-parallel splits)
    for (int it = 0; it < 3; it++) {
        dots_softmax<<<Bb * 4, blk, 0, stream>>>(qbuf, kb, attnb);
        updates_kernel<<<Bb * Hh, dim3(512), 0, stream>>>(attnb, vb, upd);
        gru_mm<<<dim3(Bb, 4), blk, 0, stream>>>(upd, slots, wihT, whhT,
                                                gru_bih, gru_bhh, gxh);
        gate_ffn1<<<dim3(Bb, 4), blk, 0, stream>>>(gxh, slots, slots2, fw1T,
                                                   ffn_ln_g, ffn_ln_b, ffn_b1, h1b);
        ffn2_mm<<<dim3(Bb, 4), blk, 0, stream>>>(h1b, slots2, slots, fw2T, ffn_b2);
        if (it < 2)
            ln_q<<<Bb, dim3(512), 0, stream>>>(slots, qbuf, q_wT, ns_g, ns_b);
    }

    // 4) selection + masked x
    select_kernel<<<Bb, blk, 0, stream>>>(slots, sel_w1, sel_b1, sel_w2, sel_b2, dec, xb);

    // 5) GAT layers, phase-split kernels
    for (int l = 0; l < 2; l++) {
        const ushort* gWT = l ? gW1T : gW0T;
        const ushort* g1T = l ? gf1bT : gf1aT;
        const ushort* g2T = l ? gf2bT : gf2aT;
        gat_attn<<<Bb, blk, 0, stream>>>(xb, dec, gWT, gat_a + l * 512,
            gat_ln_g + l * 256, gat_ln_b + l * 256,
            gat_fln_g + l * 256, gat_fln_b + l * 256, yF, ylnb);
        gat_ffn1<<<dim3(Bb, 4), blk, 0, stream>>>(ylnb, g1T, gat_fb1 + l * 1024, gh1);
        gat_ffn2<<<dim3(Bb, 4), blk, 0, stream>>>(gh1, yF, g2T, gat_fb2 + l * 256,
            l ? (float*)d_out : xb);
    }
}

// Round 28
// 563.669 us; speedup vs baseline: 1.1173x; 1.1173x over previous
//
#include <hip/hip_runtime.h>
#include <math.h>

// Problem constants
#define Bb 64
#define Nn 1024
#define FDd 768
#define Dd 256
#define KSs 8
#define TSs 12
#define Hh 4
#define HDd 64

typedef __attribute__((ext_vector_type(8))) short bf16x8;
typedef __attribute__((ext_vector_type(4))) float f32x4;

__device__ __forceinline__ ushort f2bf(float x) {
    union { float f; uint u; } v; v.f = x;
    uint r = v.u + 0x7FFFu + ((v.u >> 16) & 1u);   // RNE
    return (ushort)(r >> 16);
}
__device__ __forceinline__ float bf2f(ushort x) {
    union { uint u; float f; } v; v.u = ((uint)x) << 16;
    return v.f;
}
__device__ __forceinline__ uint pack2(float a, float b) {
    return (uint)f2bf(a) | ((uint)f2bf(b) << 16);
}
__device__ __forceinline__ float waveSum(float v) {
    #pragma unroll
    for (int o = 32; o > 0; o >>= 1) v += __shfl_xor(v, o);
    return v;
}
__device__ __forceinline__ float geluf(float v) {
    return 0.5f * v * (1.f + erff(v * 0.70710678118654752f));
}
__device__ __forceinline__ float sigm(float x) { return 1.f / (1.f + expf(-x)); }

// ---- A-fragment loader: 16-row LDS tile, lda in ushorts ----
__device__ __forceinline__ void load_af(bf16x8* af, const ushort* Alds, int lda, int lr, int lk)
{
    #pragma unroll
    for (int c = 0; c < 8; c++)
        af[c] = *(const bf16x8*)(Alds + lr * lda + c * 32 + lk * 8);
}

// ---- pipelined weight-stream matmul, K=256: NT 16-col tiles, depth-2 B prefetch ----
template<int NT, typename F>
__device__ __forceinline__ void mm_stream256(const bf16x8* af,
    const ushort* __restrict__ WT, int n0, int lr, int lk, F&& emit)
{
    const ushort* base = WT + (size_t)(n0 + lr) * 256 + lk * 8;
    bf16x8 bA[8], bB[8], bC[8];
    #pragma unroll
    for (int c = 0; c < 8; c++) bA[c] = *(const bf16x8*)(base + c * 32);
    if (NT > 1) {
        const ushort* nb = base + (size_t)16 * 256;
        #pragma unroll
        for (int c = 0; c < 8; c++) bB[c] = *(const bf16x8*)(nb + c * 32);
    }
    #pragma unroll
    for (int nt = 0; nt < NT; nt++) {
        const bf16x8* bc = (nt % 3 == 0) ? bA : (nt % 3 == 1) ? bB : bC;
        bf16x8* bn = (nt % 3 == 0) ? bC : (nt % 3 == 1) ? bA : bB;
        if (nt + 2 < NT) {
            const ushort* nb = base + (size_t)(nt + 2) * 16 * 256;
            #pragma unroll
            for (int c = 0; c < 8; c++) bn[c] = *(const bf16x8*)(nb + c * 32);
        }
        f32x4 a0 = {0.f, 0.f, 0.f, 0.f}, a1 = {0.f, 0.f, 0.f, 0.f};
        #pragma unroll
        for (int c = 0; c < 8; c += 2) a0 = __builtin_amdgcn_mfma_f32_16x16x32_bf16(af[c], bc[c], a0, 0, 0, 0);
        #pragma unroll
        for (int c = 1; c < 8; c += 2) a1 = __builtin_amdgcn_mfma_f32_16x16x32_bf16(af[c], bc[c], a1, 0, 0, 0);
        emit(nt, a0 + a1);
    }
}

// ---- pipelined matmul K=1024 (A in LDS [16][lda]), NT2 n-tiles, depth-2 prefetch ----
template<int NT2, typename F>
__device__ __forceinline__ void mm_stream_1024(const ushort* Alds, int lda,
    const ushort* __restrict__ WT, int n0, int lr, int lk, F&& emit)
{
    f32x4 acc[NT2] = {};
    bf16x8 bA[8], bB[8], bC[8];
    {
        const ushort* nb = WT + (size_t)(n0 + lr) * 1024 + lk * 8;
        #pragma unroll
        for (int c = 0; c < 8; c++) bA[c] = *(const bf16x8*)(nb + c * 32);
    }
    if (4 * NT2 > 1) {
        const int kc1 = 1 / NT2, nt1 = 1 % NT2;
        const ushort* nb = WT + (size_t)(n0 + nt1 * 16 + lr) * 1024 + kc1 * 256 + lk * 8;
        #pragma unroll
        for (int c = 0; c < 8; c++) bB[c] = *(const bf16x8*)(nb + c * 32);
    }
    #pragma unroll
    for (int kc = 0; kc < 4; kc++) {
        bf16x8 af[8];
        #pragma unroll
        for (int c = 0; c < 8; c++)
            af[c] = *(const bf16x8*)(Alds + lr * lda + kc * 256 + c * 32 + lk * 8);
        #pragma unroll
        for (int nt = 0; nt < NT2; nt++) {
            const int step = kc * NT2 + nt;
            const bf16x8* bc = (step % 3 == 0) ? bA : (step % 3 == 1) ? bB : bC;
            bf16x8* bn = (step % 3 == 0) ? bC : (step % 3 == 1) ? bA : bB;
            if (step + 2 < 4 * NT2) {
                const int kc2 = (step + 2) / NT2, nt2 = (step + 2) % NT2;
                const ushort* nb = WT + (size_t)(n0 + nt2 * 16 + lr) * 1024 + kc2 * 256 + lk * 8;
                #pragma unroll
                for (int c = 0; c < 8; c++) bn[c] = *(const bf16x8*)(nb + c * 32);
            }
            #pragma unroll
            for (int c = 0; c < 8; c++)
                acc[nt] = __builtin_amdgcn_mfma_f32_16x16x32_bf16(af[c], bc[c], acc[nt], 0, 0, 0);
        }
    }
    #pragma unroll
    for (int nt = 0; nt < NT2; nt++) emit(nt, acc[nt]);
}

// LN of a 256-wide f32 LDS row -> bf16 LDS row (one full wave)
__device__ __forceinline__ void ln_row_bf(const float* __restrict__ rowF,
    ushort* __restrict__ rowU, const float* __restrict__ g,
    const float* __restrict__ b, int lane)
{
    float4 x = *(const float4*)&rowF[lane * 4];
    float m = waveSum(x.x + x.y + x.z + x.w) * (1.f / 256.f);
    float d0 = x.x - m, d1 = x.y - m, d2 = x.z - m, d3 = x.w - m;
    float v = waveSum(d0 * d0 + d1 * d1 + d2 * d2 + d3 * d3) * (1.f / 256.f);
    float inv = 1.f / sqrtf(v + 1e-5f);
    float4 gg = *(const float4*)&g[lane * 4];
    float4 bb = *(const float4*)&b[lane * 4];
    ushort4 o;
    o.x = f2bf(d0 * inv * gg.x + bb.x); o.y = f2bf(d1 * inv * gg.y + bb.y);
    o.z = f2bf(d2 * inv * gg.z + bb.z); o.w = f2bf(d3 * inv * gg.w + bb.w);
    *(ushort4*)&rowU[lane * 4] = o;
}

// ============ big bf16 MFMA GEMM: C[M][256], M-tile 64 (grid.y selects W/C) ============
// DO_LN: fuse bias + double-LN into the epilogue (LDS bf16 tile), bit-identical to
// the separate gemm-store -> ln2b_wave path. Staging LDS is dead by then and reused.
#define LPAD 40
template<bool A_F32, bool DO_LN>
__global__ __launch_bounds__(256) void gemm_mfma(const void* __restrict__ Ap,
    const ushort* __restrict__ WTa, const ushort* __restrict__ WTb,
    const float* __restrict__ bias,
    const float* __restrict__ g1, const float* __restrict__ b1,
    const float* __restrict__ g2, const float* __restrict__ b2,
    ushort* __restrict__ Ca, ushort* __restrict__ Cb, int M, int K)
{
    constexpr int SMEM_USHORTS = DO_LN ? (64 * 264) : (64 * LPAD + 256 * LPAD);
    __shared__ __align__(16) ushort smem[SMEM_USHORTS];
    ushort* As = smem;                    // [64][LPAD]
    ushort* Bs = smem + 64 * LPAD;        // [256][LPAD]
    ushort* xS = smem;                    // [64][264] (DO_LN epilogue, aliases staging)
    const ushort* WT = blockIdx.y ? WTb : WTa;
    ushort* C = blockIdx.y ? Cb : Ca;
    const int t = threadIdx.x;
    const int m0 = blockIdx.x * 64;
    const int lane = t & 63, wv = t >> 6;
    const int lr = lane & 15, lk = lane >> 4;

    f32x4 acc[4][4] = {};

    const float*  agf = (const float*)Ap  + (size_t)(m0 + (t >> 2)) * K + (t & 3) * 8;
    const ushort* agb = (const ushort*)Ap + (size_t)(m0 + (t >> 2)) * K + (t & 3) * 8;
    const ushort* bg  = WT + (size_t)(t >> 2) * K + (t & 3) * 8;

    float4 fA0, fA1; int4 iA0; int4 iB0, iB1, iB2, iB3;

#define GLOAD(k0) do { \
        if (A_F32) { \
            fA0 = *(const float4*)(agf + (k0)); fA1 = *(const float4*)(agf + (k0) + 4); \
        } else { \
            iA0 = *(const int4*)(agb + (k0)); \
        } \
        iB0 = *(const int4*)(bg + (k0)); \
        iB1 = *(const int4*)(bg + (size_t)64  * K + (k0)); \
        iB2 = *(const int4*)(bg + (size_t)128 * K + (k0)); \
        iB3 = *(const int4*)(bg + (size_t)192 * K + (k0)); \
    } while (0)

#define LSTORE() do { \
        if (A_F32) { \
            int4 w; \
            w.x = pack2(fA0.x, fA0.y); w.y = pack2(fA0.z, fA0.w); \
            w.z = pack2(fA1.x, fA1.y); w.w = pack2(fA1.z, fA1.w); \
            *(int4*)&As[(t >> 2) * LPAD + (t & 3) * 8] = w; \
        } else { \
            *(int4*)&As[(t >> 2) * LPAD + (t & 3) * 8] = iA0; \
        } \
        *(int4*)&Bs[(t >> 2) * LPAD + (t & 3) * 8]         = iB0; \
        *(int4*)&Bs[(64 + (t >> 2)) * LPAD + (t & 3) * 8]  = iB1; \
        *(int4*)&Bs[(128 + (t >> 2)) * LPAD + (t & 3) * 8] = iB2; \
        *(int4*)&Bs[(192 + (t >> 2)) * LPAD + (t & 3) * 8] = iB3; \
    } while (0)

    GLOAD(0);
    for (int k0 = 0; k0 < K; k0 += 32) {
        LSTORE();
        __syncthreads();
        bf16x8 af[4], bfr[4];
        #pragma unroll
        for (int mi = 0; mi < 4; mi++)
            af[mi] = *(const bf16x8*)&As[(mi * 16 + lr) * LPAD + lk * 8];
        #pragma unroll
        for (int ni = 0; ni < 4; ni++)
            bfr[ni] = *(const bf16x8*)&Bs[(wv * 64 + ni * 16 + lr) * LPAD + lk * 8];
        if (k0 + 32 < K) GLOAD(k0 + 32);
        #pragma unroll
        for (int mi = 0; mi < 4; mi++)
            #pragma unroll
            for (int ni = 0; ni < 4; ni++)
                acc[mi][ni] = __builtin_amdgcn_mfma_f32_16x16x32_bf16(af[mi], bfr[ni], acc[mi][ni], 0, 0, 0);
        __syncthreads();
    }
#undef GLOAD
#undef LSTORE
    if (DO_LN) {
        // bias + bf16 -> xS (staging LDS is dead; last loop iteration ended with barrier)
        #pragma unroll
        for (int mi = 0; mi < 4; mi++) {
            int row = mi * 16 + lk * 4;
            #pragma unroll
            for (int ni = 0; ni < 4; ni++) {
                int col = wv * 64 + ni * 16 + lr;
                float bv = bias[col];
                #pragma unroll
                for (int r = 0; r < 4; r++)
                    xS[(row + r) * 264 + col] = f2bf(acc[mi][ni][r] + bv);
            }
        }
        __syncthreads();
        // double-LN in place: wave wv handles rows wv*16 .. wv*16+15
        #pragma unroll
        for (int rr = 0; rr < 16; rr++) {
            int row = wv * 16 + rr;
            ushort4 u = *(const ushort4*)&xS[row * 264 + lane * 4];
            float x0 = bf2f(u.x), x1 = bf2f(u.y), x2 = bf2f(u.z), x3 = bf2f(u.w);
            float m = waveSum(x0 + x1 + x2 + x3) * (1.f / 256.f);
            float d0 = x0 - m, d1 = x1 - m, d2 = x2 - m, d3 = x3 - m;
            float v = waveSum(d0 * d0 + d1 * d1 + d2 * d2 + d3 * d3) * (1.f / 256.f);
            float inv = 1.f / sqrtf(v + 1e-5f);
            float4 gg = *(const float4*)&g1[lane * 4];
            float4 bbv = *(const float4*)&b1[lane * 4];
            float y0 = d0 * inv * gg.x + bbv.x, y1 = d1 * inv * gg.y + bbv.y;
            float y2 = d2 * inv * gg.z + bbv.z, y3 = d3 * inv * gg.w + bbv.w;
            float m2 = waveSum(y0 + y1 + y2 + y3) * (1.f / 256.f);
            float e0 = y0 - m2, e1 = y1 - m2, e2 = y2 - m2, e3 = y3 - m2;
            float v2 = waveSum(e0 * e0 + e1 * e1 + e2 * e2 + e3 * e3) * (1.f / 256.f);
            float inv2 = 1.f / sqrtf(v2 + 1e-5f);
            float4 g2v = *(const float4*)&g2[lane * 4];
            float4 b2v = *(const float4*)&b2[lane * 4];
            ushort4 o;
            o.x = f2bf(e0 * inv2 * g2v.x + b2v.x); o.y = f2bf(e1 * inv2 * g2v.y + b2v.y);
            o.z = f2bf(e2 * inv2 * g2v.z + b2v.z); o.w = f2bf(e3 * inv2 * g2v.w + b2v.w);
            *(ushort4*)&xS[row * 264 + lane * 4] = o;
        }
        __syncthreads();
        // coalesced store: 4096 ushort4 over 256 threads
        for (int idx = t; idx < 4096; idx += 256) {
            int row = idx >> 6, cg = (idx & 63) * 4;
            *(ushort4*)&C[(size_t)(m0 + row) * 256 + cg] =
                *(const ushort4*)&xS[row * 264 + cg];
        }
    } else {
        #pragma unroll
        for (int mi = 0; mi < 4; mi++) {
            int grow = m0 + mi * 16 + lk * 4;
            #pragma unroll
            for (int ni = 0; ni < 4; ni++) {
                int gcol = wv * 64 + ni * 16 + lr;
                float bv = bias ? bias[gcol] : 0.f;
                #pragma unroll
                for (int r = 0; r < 4; r++)
                    C[(size_t)(grow + r) * 256 + gcol] = f2bf(acc[mi][ni][r] + bv);
            }
        }
    }
}

// ---------------- tiled transpose+cast for all 14 weight matrices ----------------
struct PrepArgsT {
    const float* src[14];
    ushort* dst[14];
    int K[14];
    int N[14];
    int tstart[15];
};
__global__ __launch_bounds__(256) void prep_tiled(PrepArgsT pa)
{
    __shared__ float s[32][33];
    int tile = blockIdx.x;
    int seg = 0;
    while (tile >= pa.tstart[seg + 1]) seg++;
    int lt = tile - pa.tstart[seg];
    int K = pa.K[seg], N = pa.N[seg];
    int tpr = N >> 5;
    int k0 = (lt / tpr) << 5, n0 = (lt % tpr) << 5;
    const float* src = pa.src[seg];
    ushort* dst = pa.dst[seg];
    int r = threadIdx.x >> 5, c = threadIdx.x & 31;
    #pragma unroll
    for (int rr = 0; rr < 32; rr += 8)
        s[rr + r][c] = src[(size_t)(k0 + rr + r) * N + n0 + c];
    __syncthreads();
    #pragma unroll
    for (int rr = 0; rr < 32; rr += 8)
        dst[(size_t)(n0 + rr + r) * K + k0 + c] = f2bf(s[c][rr + r]);
}

// ---------------- slots init + LN + q (per batch, 8 waves) ----------------
__global__ __launch_bounds__(512) void slot_init_q(
    const float* __restrict__ mu, const float* __restrict__ ls,
    const float* __restrict__ eps, float* __restrict__ slots_g,
    float* __restrict__ qbuf, const ushort* __restrict__ qwT,
    const float* __restrict__ ns_g, const float* __restrict__ ns_b)
{
    __shared__ float sF[16 * 256];
    __shared__ __align__(16) ushort sU[16 * 264];
    int b = blockIdx.x, t = threadIdx.x;
    int lane = t & 63, wv = t >> 6, lr = lane & 15, lk = lane >> 4;
    for (int idx = t; idx < 4096; idx += 512) {
        int i = idx >> 8, c = idx & 255;
        float v = 0.f;
        if (i < 12) {
            int md = i * 256 + c;
            v = mu[md] + expf(ls[md]) * eps[(size_t)(b * 12 + i) * 256 + c];
            slots_g[(size_t)(b * 12 + i) * 256 + c] = v;
        }
        sF[idx] = v;
        sU[i * 264 + c] = 0;
    }
    __syncthreads();
    ln_row_bf(sF + wv * 256, sU + wv * 264, ns_g, ns_b, lane);
    if (wv < 4) ln_row_bf(sF + (8 + wv) * 256, sU + (8 + wv) * 264, ns_g, ns_b, lane);
    __syncthreads();
    bf16x8 af[8];
    load_af(af, sU, 264, lr, lk);
    mm_stream256<2>(af, qwT, wv * 32, lr, lk, [&](int nt, f32x4 a) {
        int n = wv * 32 + nt * 16 + lr;
        #pragma unroll
        for (int r = 0; r < 4; r++) {
            int m = lk * 4 + r;
            if (m < 12) qbuf[(size_t)(b * 12 + m) * 256 + n] = a[r] * 0.125f;
        }
    });
}

// ---------------- fused dots + softmax48 (attn stored bf16) ----------------
__global__ __launch_bounds__(256) void dots_softmax(const float* __restrict__ qb,
    const ushort* __restrict__ kb, ushort* __restrict__ attnb)
{
    int b = blockIdx.x >> 2, chunk = blockIdx.x & 3;
    int t = threadIdx.x;
    int j = chunk * 256 + t;
    const float* qbase = qb + (size_t)b * 12 * 256;
    float a48[48];
    #pragma unroll
    for (int h = 0; h < 4; h++) {
        const uint* kp = (const uint*)(kb + (size_t)(b * Nn + j) * 256 + h * 64);
        float kr[64];
        #pragma unroll
        for (int c = 0; c < 8; c++) {
            int4 k4 = *(const int4*)(kp + c * 4);
            uint u0 = (uint)k4.x, u1 = (uint)k4.y, u2 = (uint)k4.z, u3 = (uint)k4.w;
            kr[c * 8 + 0] = __uint_as_float(u0 << 16); kr[c * 8 + 1] = __uint_as_float(u0 & 0xffff0000u);
            kr[c * 8 + 2] = __uint_as_float(u1 << 16); kr[c * 8 + 3] = __uint_as_float(u1 & 0xffff0000u);
            kr[c * 8 + 4] = __uint_as_float(u2 << 16); kr[c * 8 + 5] = __uint_as_float(u2 & 0xffff0000u);
            kr[c * 8 + 6] = __uint_as_float(u3 << 16); kr[c * 8 + 7] = __uint_as_float(u3 & 0xffff0000u);
        }
        #pragma unroll
        for (int i = 0; i < 12; i++) {
            const float* qr = qbase + i * 256 + h * 64;
            float acc = 0.f;
            #pragma unroll
            for (int c = 0; c < 64; c++) acc += kr[c] * qr[c];
            a48[i * 4 + h] = acc;
        }
    }
    float m = -1e30f;
    #pragma unroll
    for (int idx = 0; idx < 48; idx++) m = fmaxf(m, a48[idx]);
    float s = 0.f;
    #pragma unroll
    for (int idx = 0; idx < 48; idx++) { a48[idx] = expf(a48[idx] - m); s += a48[idx]; }
    float inv = 1.f / s;
    #pragma unroll
    for (int idx = 0; idx < 48; idx++)
        attnb[(size_t)(b * 48 + idx) * Nn + j] = f2bf(a48[idx] * inv);
}

// ---------------- updates with fused rowsum; bf16x8 (16B) v-loads ----------------
// Lane map: jj = lane>>3 (8 j per wave), dg = lane&7 (bf16x8 over d).
// Per wave-load: 8 x 128B contiguous chunks (1KB). 16 iterations total.
// 3-level shfl fold (8,16,32); lane<8 writes LDS; w==0 epilogue unchanged.
__global__ __launch_bounds__(512) void updates_kernel(const ushort* __restrict__ attnb,
    const ushort* __restrict__ vb, float* __restrict__ upd)
{
    int b = blockIdx.x >> 2, h = blockIdx.x & 3;
    int t = threadIdx.x, w = t >> 6, lane = t & 63;
    int jj = lane >> 3, dg = lane & 7;
    float acc[12][8] = {};
    float ra[12] = {};
    float accv[8] = {};
    for (int jb = w * 8; jb < Nn; jb += 64) {
        int j = jb + jj;
        bf16x8 v8 = *(const bf16x8*)&vb[(size_t)(b * Nn + j) * Dd + h * HDd + dg * 8];
        float vv[8];
        #pragma unroll
        for (int r = 0; r < 8; r++) { vv[r] = bf2f((ushort)v8[r]); accv[r] += vv[r]; }
        #pragma unroll
        for (int i = 0; i < 12; i++) {
            float a = bf2f(attnb[(size_t)(b * 48 + i * 4 + h) * Nn + j]);
            #pragma unroll
            for (int r = 0; r < 8; r++) acc[i][r] += a * vv[r];
            ra[i] += a;
        }
    }
    // fold the 8 jj groups onto matching dg lanes (xor 8, 16, 32)
    #pragma unroll
    for (int i = 0; i < 12; i++) {
        #pragma unroll
        for (int r = 0; r < 8; r++) {
            acc[i][r] += __shfl_xor(acc[i][r], 8);
            acc[i][r] += __shfl_xor(acc[i][r], 16);
            acc[i][r] += __shfl_xor(acc[i][r], 32);
        }
        ra[i] += __shfl_xor(ra[i], 8);
        ra[i] += __shfl_xor(ra[i], 16);
        ra[i] += __shfl_xor(ra[i], 32);
    }
    #pragma unroll
    for (int r = 0; r < 8; r++) {
        accv[r] += __shfl_xor(accv[r], 8);
        accv[r] += __shfl_xor(accv[r], 16);
        accv[r] += __shfl_xor(accv[r], 32);
    }
    __shared__ float redA[8][12][64];
    __shared__ float redV[8][64];
    __shared__ float redR[8][12];
    if (lane < 8) {
        #pragma unroll
        for (int i = 0; i < 12; i++)
            #pragma unroll
            for (int r = 0; r < 8; r++)
                redA[w][i][lane * 8 + r] = acc[i][r];
        #pragma unroll
        for (int r = 0; r < 8; r++) redV[w][lane * 8 + r] = accv[r];
        if (lane == 0) {
            #pragma unroll
            for (int i = 0; i < 12; i++) redR[w][i] = ra[i];
        }
    }
    __syncthreads();
    if (w == 0) {
        float sv = 0.f;
        #pragma unroll
        for (int ww = 0; ww < 8; ww++) sv += redV[ww][lane];
        #pragma unroll
        for (int i = 0; i < 12; i++) {
            float s = 0.f, rs = 0.f;
            #pragma unroll
            for (int ww = 0; ww < 8; ww++) { s += redA[ww][i][lane]; rs += redR[ww][i]; }
            upd[(size_t)(b * TSs + i) * Dd + h * HDd + lane] = (s + 1e-8f * sv) / (rs + 1e-8f);
        }
    }
}

// ---------------- GRU matmuls, column-parallel: grid (64 batches, 4 quarters) ----------------
__global__ __launch_bounds__(256) void gru_mm(const float* __restrict__ upd,
    const float* __restrict__ slots_g,
    const ushort* __restrict__ wihT, const ushort* __restrict__ whhT,
    const float* __restrict__ bih, const float* __restrict__ bhh,
    float* __restrict__ gxh)
{
    __shared__ __align__(16) ushort sU[16 * 264], sS[16 * 264];
    int b = blockIdx.x, q = blockIdx.y, t = threadIdx.x;
    int lane = t & 63, wv = t >> 6, lr = lane & 15, lk = lane >> 4;
    for (int idx = t; idx < 4096; idx += 256) {
        int i = idx >> 8, c = idx & 255;
        float uv = 0.f, sv = 0.f;
        if (i < 12) {
            uv = upd[(size_t)(b * 12 + i) * 256 + c];
            sv = slots_g[(size_t)(b * 12 + i) * 256 + c];
        }
        sU[i * 264 + c] = f2bf(uv);
        sS[i * 264 + c] = f2bf(sv);
    }
    __syncthreads();
    bool ih = (wv < 2);
    bf16x8 af[8];
    load_af(af, ih ? sU : sS, 264, lr, lk);
    const ushort* W = ih ? wihT : whhT;
    const float* bias = ih ? bih : bhh;
    float* outp = gxh + (size_t)(b * 2 + (ih ? 0 : 1)) * 12 * 768;
    int n0 = q * 192 + (wv & 1) * 96;
    mm_stream256<6>(af, W, n0, lr, lk, [&](int nt, f32x4 a) {
        int n = n0 + nt * 16 + lr;
        float bv = bias[n];
        #pragma unroll
        for (int r = 0; r < 4; r++) {
            int m = lk * 4 + r;
            if (m < 12) outp[m * 768 + n] = a[r] + bv;
        }
    });
}

// ---------------- gate + FFN-LN + FFN1 quarter: grid (64, 4) ----------------
__global__ __launch_bounds__(256) void gate_ffn1(const float* __restrict__ gxh,
    const float* __restrict__ slots_g, float* __restrict__ slots2,
    const ushort* __restrict__ fw1T,
    const float* __restrict__ fln_g, const float* __restrict__ fln_b,
    const float* __restrict__ f_b1, ushort* __restrict__ h1b)
{
    __shared__ float sF[12 * 256];
    __shared__ __align__(16) ushort sU[16 * 264];
    int b = blockIdx.x, q = blockIdx.y, t = threadIdx.x;
    int lane = t & 63, wv = t >> 6, lr = lane & 15, lk = lane >> 4;
    for (int idx = t; idx < 1056; idx += 256) sU[12 * 264 + idx] = 0;
    for (int idx = t; idx < 3072; idx += 256) {
        int i = idx >> 8, c = idx & 255;
        const float* gx = gxh + (size_t)(b * 2) * 12 * 768 + i * 768;
        const float* gh = gxh + (size_t)(b * 2 + 1) * 12 * 768 + i * 768;
        float r = sigm(gx[c] + gh[c]);
        float z = sigm(gx[256 + c] + gh[256 + c]);
        float nv = tanhf(gx[512 + c] + r * gh[512 + c]);
        float hp = slots_g[(size_t)(b * 12 + i) * 256 + c];
        float out = (1.f - z) * nv + z * hp;
        sF[idx] = out;
        if (q == 0) slots2[(size_t)(b * 12 + i) * 256 + c] = out;
    }
    __syncthreads();
    for (int rr = 0; rr < 3; rr++) {
        int row = wv * 3 + rr;
        ln_row_bf(sF + row * 256, sU + row * 264, fln_g, fln_b, lane);
    }
    __syncthreads();
    bf16x8 af[8];
    load_af(af, sU, 264, lr, lk);
    int n0 = q * 256 + wv * 64;
    mm_stream256<4>(af, fw1T, n0, lr, lk, [&](int nt, f32x4 a) {
        int n = n0 + nt * 16 + lr;
        float bv = f_b1[n];
        #pragma unroll
        for (int r = 0; r < 4; r++) {
            int m = lk * 4 + r;
            if (m < 12) h1b[(size_t)(b * 12 + m) * 1024 + n] = f2bf(geluf(a[r] + bv));
        }
    });
}

// ---------------- FFN2 matmul + residual, column-quarter: grid (64, 4) ----------------
// Writes slots_g = ffn2(h1) + bias + slots2; LN+q moved to ln_q (4x CU coverage).
__global__ __launch_bounds__(256) void ffn2_mm(const ushort* __restrict__ h1b,
    const float* __restrict__ slots2, float* __restrict__ slots_g,
    const ushort* __restrict__ fw2T, const float* __restrict__ f_b2)
{
    __shared__ __align__(16) ushort hS[16 * 1032];
    int b = blockIdx.x, q = blockIdx.y, t = threadIdx.x;
    int lane = t & 63, wv = t >> 6, lr = lane & 15, lk = lane >> 4;
    for (int ch = t; ch < 2048; ch += 256) {
        int i = ch >> 7, c8 = (ch & 127) * 8;
        int4 v = {0, 0, 0, 0};
        if (i < 12) v = *(const int4*)&h1b[(size_t)(b * 12 + i) * 1024 + c8];
        *(int4*)&hS[i * 1032 + c8] = v;
    }
    __syncthreads();
    int n0 = q * 64 + wv * 16;
    mm_stream_1024<1>(hS, 1032, fw2T, n0, lr, lk, [&](int nt, f32x4 a) {
        (void)nt;
        int n = n0 + lr;
        float bv = f_b2[n];
        #pragma unroll
        for (int r = 0; r < 4; r++) {
            int m = lk * 4 + r;
            if (m < 12)
                slots_g[(size_t)(b * 12 + m) * 256 + n] =
                    a[r] + bv + slots2[(size_t)(b * 12 + m) * 256 + n];
        }
    });
}

// ---------------- LN(slots) + q projection: grid 64, 8 waves (it < 2 only) ----------------
__global__ __launch_bounds__(512) void ln_q(const float* __restrict__ slots_g,
    float* __restrict__ qbuf, const ushort* __restrict__ qwT,
    const float* __restrict__ ns_g, const float* __restrict__ ns_b)
{
    __shared__ float sF[12 * 256];
    __shared__ __align__(16) ushort sU[16 * 264];
    int b = blockIdx.x, t = threadIdx.x;
    int lane = t & 63, wv = t >> 6, lr = lane & 15, lk = lane >> 4;
    for (int idx = t; idx < 3072; idx += 512) sF[idx] = slots_g[(size_t)b * 3072 + idx];
    for (int idx = t; idx < 1056; idx += 512) sU[12 * 264 + idx] = 0;
    __syncthreads();
    ln_row_bf(sF + wv * 256, sU + wv * 264, ns_g, ns_b, lane);
    if (wv < 4) ln_row_bf(sF + (8 + wv) * 256, sU + (8 + wv) * 264, ns_g, ns_b, lane);
    __syncthreads();
    bf16x8 af[8];
    load_af(af, sU, 264, lr, lk);
    mm_stream256<2>(af, qwT, wv * 32, lr, lk, [&](int nt, f32x4 a) {
        int n = wv * 32 + nt * 16 + lr;
        #pragma unroll
        for (int r = 0; r < 4; r++) {
            int m = lk * 4 + r;
            if (m < 12) qbuf[(size_t)(b * 12 + m) * 256 + n] = a[r] * 0.125f;
        }
    });
}

// ---------------- selection head + masked x write ----------------
__global__ __launch_bounds__(256) void select_kernel(const float* __restrict__ slots,
    const float* __restrict__ w1, const float* __restrict__ b1,
    const float* __restrict__ w2, const float* __restrict__ b2,
    float* __restrict__ dec, float* __restrict__ xout)
{
    int b = blockIdx.x, t = threadIdx.x;
    __shared__ float t1[8][128];
    __shared__ float lg[8][2];
    __shared__ float dsh[8];
    const float* obj = slots + (size_t)b * TSs * Dd;
    #pragma unroll
    for (int u = 0; u < 4; u++) {
        int idx = t + 256 * u;
        int k = idx >> 7, c = idx & 127;
        float s = b1[c];
        for (int d = 0; d < 256; d++) s += obj[k * 256 + d] * w1[d * 128 + c];
        t1[k][c] = fmaxf(s, 0.f);
    }
    __syncthreads();
    if (t < 16) {
        int k = t >> 1, o = t & 1;
        float s = b2[o];
        for (int c = 0; c < 128; c++) s += t1[k][c] * w2[c * 2 + o];
        lg[k][o] = s;
    }
    __syncthreads();
    if (t == 0) {
        float dv[8]; float sum = 0.f;
        for (int k = 0; k < 8; k++) { dv[k] = (lg[k][1] > lg[k][0]) ? 1.f : 0.f; sum += dv[k]; }
        float needed = fmaxf(2.f - sum, 0.f);
        float rank = 0.f;
        for (int k = 0; k < 8; k++) {
            float inact = 1.f - dv[k];
            rank += inact;
            if (inact > 0.f && rank <= needed) dv[k] = 1.f;
            dsh[k] = dv[k];
            dec[b * 8 + k] = dv[k];
        }
    }
    __syncthreads();
    for (int idx = t; idx < 2048; idx += 256) {
        int k = idx >> 8, c = idx & 255;
        xout[(size_t)(b * 8 + k) * 256 + c] = obj[k * 256 + c] * dsh[k];
    }
}

// ---------------- GAT: LN + proj + attention + residual + post-LN: grid 64 ----------------
__global__ __launch_bounds__(256) void gat_attn(const float* __restrict__ xin,
    const float* __restrict__ dec, const ushort* __restrict__ gWT,
    const float* __restrict__ av,
    const float* __restrict__ lng, const float* __restrict__ lnb,
    const float* __restrict__ flng, const float* __restrict__ flnb,
    float* __restrict__ yF, ushort* __restrict__ ylnb)
{
    __shared__ float xF[8 * 256];
    __shared__ float hmF[8 * 256];
    __shared__ __align__(16) ushort sU[16 * 264];
    __shared__ float ei[8][4], ej[8][4], al[8][4][8], ds[8];
    int b = blockIdx.x, t = threadIdx.x;
    int lane = t & 63, wv = t >> 6, lr = lane & 15, lk = lane >> 4;

    for (int idx = t; idx < 2048; idx += 256) xF[idx] = xin[(size_t)b * 2048 + idx];
    for (int idx = t; idx < 2112; idx += 256) sU[8 * 264 + idx] = 0;
    if (t < 8) ds[t] = dec[b * 8 + t];
    __syncthreads();
    ln_row_bf(xF + (wv * 2) * 256, sU + (wv * 2) * 264, lng, lnb, lane);
    ln_row_bf(xF + (wv * 2 + 1) * 256, sU + (wv * 2 + 1) * 264, lng, lnb, lane);
    __syncthreads();
    {
        bf16x8 af[8];
        load_af(af, sU, 264, lr, lk);
        mm_stream256<4>(af, gWT, wv * 64, lr, lk, [&](int nt, f32x4 a) {
            int n = wv * 64 + nt * 16 + lr;
            #pragma unroll
            for (int r = 0; r < 4; r++) {
                int m = lk * 4 + r;
                if (m < 8) hmF[m * 256 + n] = a[r];
            }
        });
    }
    __syncthreads();
    {
        int pair = t >> 3, sub = t & 7;
        int k = pair >> 2, h = pair & 3;
        const float* hrow = hmF + k * 256 + h * 64 + sub * 8;
        float s1 = 0.f, s2 = 0.f;
        #pragma unroll
        for (int d = 0; d < 8; d++) {
            float hv = hrow[d];
            s1 += hv * av[h * 128 + sub * 8 + d];
            s2 += hv * av[h * 128 + 64 + sub * 8 + d];
        }
        #pragma unroll
        for (int o = 1; o < 8; o <<= 1) { s1 += __shfl_xor(s1, o); s2 += __shfl_xor(s2, o); }
        if (sub == 0) { ei[k][h] = s1; ej[k][h] = s2; }
    }
    __syncthreads();
    {
        int k = t >> 5, h = (t >> 3) & 3, n = t & 7;
        float e = ei[k][h] + ej[n][h];
        e = (e >= 0.f) ? e : 0.2f * e;
        if (ds[k] * ds[n] == 0.f) e = -1e9f;
        float mx = e;
        #pragma unroll
        for (int o = 4; o > 0; o >>= 1) mx = fmaxf(mx, __shfl_xor(mx, o, 8));
        float ex = expf(e - mx);
        float sm = ex;
        #pragma unroll
        for (int o = 4; o > 0; o >>= 1) sm += __shfl_xor(sm, o, 8);
        al[k][h][n] = ex / sm;
    }
    __syncthreads();
    {
        int h = t >> 6, d = t & 63;
        #pragma unroll
        for (int k = 0; k < 8; k++) {
            float o = 0.f;
            #pragma unroll
            for (int n = 0; n < 8; n++) o += al[k][h][n] * hmF[n * 256 + h * 64 + d];
            xF[k * 256 + h * 64 + d] += o;
        }
    }
    __syncthreads();
    for (int idx = t; idx < 2048; idx += 256) yF[(size_t)b * 2048 + idx] = xF[idx];
    ln_row_bf(xF + (wv * 2) * 256, sU + (wv * 2) * 264, flng, flnb, lane);
    ln_row_bf(xF + (wv * 2 + 1) * 256, sU + (wv * 2 + 1) * 264, flng, flnb, lane);
    __syncthreads();
    for (int idx = t; idx < 2048; idx += 256) {
        int i = idx >> 8, c = idx & 255;
        ylnb[(size_t)b * 2048 + idx] = sU[i * 264 + c];
    }
}

// ---------------- GAT FFN1 quarter: grid (64, 4) ----------------
__global__ __launch_bounds__(256) void gat_ffn1(const ushort* __restrict__ ylnb,
    const ushort* __restrict__ g1T, const float* __restrict__ fb1,
    ushort* __restrict__ gh1)
{
    __shared__ __align__(16) ushort sU[16 * 264];
    int b = blockIdx.x, q = blockIdx.y, t = threadIdx.x;
    int lane = t & 63, wv = t >> 6, lr = lane & 15, lk = lane >> 4;
    for (int idx = t; idx < 4096; idx += 256) {
        int i = idx >> 8, c = idx & 255;
        sU[i * 264 + c] = (i < 8) ? ylnb[(size_t)b * 2048 + i * 256 + c] : 0;
    }
    __syncthreads();
    bf16x8 af[8];
    load_af(af, sU, 264, lr, lk);
    int n0 = q * 256 + wv * 64;
    mm_stream256<4>(af, g1T, n0, lr, lk, [&](int nt, f32x4 a) {
        int n = n0 + nt * 16 + lr;
        float bv = fb1[n];
        #pragma unroll
        for (int r = 0; r < 4; r++) {
            int m = lk * 4 + r;
            if (m < 8) gh1[(size_t)(b * 8 + m) * 1024 + n] = f2bf(geluf(a[r] + bv));
        }
    });
}

// ---------------- GAT FFN2 + residual: grid (64, 4), 64-col slices ----------------
__global__ __launch_bounds__(256) void gat_ffn2(const ushort* __restrict__ gh1,
    const float* __restrict__ yF, const ushort* __restrict__ g2T,
    const float* __restrict__ fb2, float* __restrict__ out)
{
    __shared__ __align__(16) ushort hS[16 * 1032];
    int b = blockIdx.x, q = blockIdx.y, t = threadIdx.x;
    int lane = t & 63, wv = t >> 6, lr = lane & 15, lk = lane >> 4;
    for (int ch = t; ch < 2048; ch += 256) {
        int i = ch >> 7, c8 = (ch & 127) * 8;
        int4 v = {0, 0, 0, 0};
        if (i < 8) v = *(const int4*)&gh1[(size_t)(b * 8 + i) * 1024 + c8];
        *(int4*)&hS[i * 1032 + c8] = v;
    }
    __syncthreads();
    int n0 = q * 64 + wv * 16;
    mm_stream_1024<1>(hS, 1032, g2T, n0, lr, lk, [&](int nt, f32x4 a) {
        (void)nt;
        int n = n0 + lr;
        float bv = fb2[n];
        #pragma unroll
        for (int r = 0; r < 4; r++) {
            int m = lk * 4 + r;
            if (m < 8) out[(size_t)(b * 8 + m) * 256 + n] = a[r] + bv + yF[(size_t)(b * 8 + m) * 256 + n];
        }
    });
}

// ======================================================================
extern "C" void kernel_launch(void* const* d_in, const int* in_sizes, int n_in,
                              void* d_out, int out_size, void* d_ws, size_t ws_size,
                              hipStream_t stream)
{
    (void)in_sizes; (void)n_in; (void)out_size; (void)ws_size;
    const float* features       = (const float*)d_in[0];
    const float* eps_noise      = (const float*)d_in[1];
    const float* in_w           = (const float*)d_in[2];
    const float* in_b           = (const float*)d_in[3];
    const float* in_ln_g        = (const float*)d_in[4];
    const float* in_ln_b        = (const float*)d_in[5];
    const float* ni_g           = (const float*)d_in[6];
    const float* ni_b           = (const float*)d_in[7];
    const float* slot_mu        = (const float*)d_in[8];
    const float* slot_log_sigma = (const float*)d_in[9];
    const float* q_w            = (const float*)d_in[10];
    const float* k_w            = (const float*)d_in[11];
    const float* v_w            = (const float*)d_in[12];
    const float* gru_wih        = (const float*)d_in[13];
    const float* gru_whh        = (const float*)d_in[14];
    const float* gru_bih        = (const float*)d_in[15];
    const float* gru_bhh        = (const float*)d_in[16];
    const float* ns_g           = (const float*)d_in[17];
    const float* ns_b           = (const float*)d_in[18];
    const float* ffn_ln_g       = (const float*)d_in[19];
    const float* ffn_ln_b       = (const float*)d_in[20];
    const float* ffn_w1         = (const float*)d_in[21];
    const float* ffn_b1         = (const float*)d_in[22];
    const float* ffn_w2         = (const float*)d_in[23];
    const float* ffn_b2         = (const float*)d_in[24];
    const float* sel_w1         = (const float*)d_in[25];
    const float* sel_b1         = (const float*)d_in[26];
    const float* sel_w2         = (const float*)d_in[27];
    const float* sel_b2         = (const float*)d_in[28];
    const float* gat_W          = (const float*)d_in[29];
    const float* gat_a          = (const float*)d_in[30];
    const float* gat_ln_g       = (const float*)d_in[31];
    const float* gat_ln_b       = (const float*)d_in[32];
    const float* gat_fln_g      = (const float*)d_in[33];
    const float* gat_fln_b      = (const float*)d_in[34];
    const float* gat_fw1        = (const float*)d_in[35];
    const float* gat_fb1        = (const float*)d_in[36];
    const float* gat_fw2        = (const float*)d_in[37];
    const float* gat_fb2        = (const float*)d_in[38];

    // ---- workspace layout ----
    ushort* kb  = (ushort*)d_ws;
    ushort* vb  = kb + 16777216;
    ushort* xnb = vb + 16777216;
    ushort* wtb = xnb + 16777216;         // 2,490,368 transposed bf16 weights
    ushort* h1b  = wtb + 2490368;         // 786,432
    ushort* ylnb = h1b + 786432;          // 131,072
    ushort* gh1  = ylnb + 131072;         // 524,288
    ushort* attnb = gh1 + 524288;         // 3,145,728 bf16 attn
    float* fbase = (float*)(attnb + 3145728);
    float* slots  = fbase;                // 196,608
    float* slots2 = slots + 196608;       // 196,608
    float* qbuf   = slots2 + 196608;      // 196,608
    float* upd    = qbuf + 196608;        // 196,608
    float* gxh    = upd + 196608;         // 1,179,648
    float* xb     = gxh + 1179648;        // 131,072
    float* yF     = xb + 131072;          // 131,072
    float* dec    = yF + 131072;          // 512

    ushort* in_wT = wtb;                  // 196608
    ushort* k_wT  = in_wT + 196608;       // 65536
    ushort* v_wT  = k_wT + 65536;
    ushort* q_wT  = v_wT + 65536;
    ushort* wihT  = q_wT + 65536;         // 196608
    ushort* whhT  = wihT + 196608;
    ushort* fw1T  = whhT + 196608;        // 262144
    ushort* fw2T  = fw1T + 262144;
    ushort* gW0T  = fw2T + 262144;        // 65536
    ushort* gW1T  = gW0T + 65536;
    ushort* gf1aT = gW1T + 65536;         // 262144
    ushort* gf1bT = gf1aT + 262144;
    ushort* gf2aT = gf1bT + 262144;
    ushort* gf2bT = gf2aT + 262144;

    dim3 blk(256);

    // 0) all weights -> bf16 [N][K], 32x32 LDS-tiled
    PrepArgsT pa;
    const float* srcs[14] = { in_w, k_w, v_w, q_w, gru_wih, gru_whh, ffn_w1, ffn_w2,
                              gat_W, gat_W + 65536, gat_fw1, gat_fw1 + 262144,
                              gat_fw2, gat_fw2 + 262144 };
    ushort* dsts[14] = { in_wT, k_wT, v_wT, q_wT, wihT, whhT, fw1T, fw2T,
                         gW0T, gW1T, gf1aT, gf1bT, gf2aT, gf2bT };
    int Ks[14]  = { 768, 256, 256, 256, 256, 256, 256, 1024, 256, 256, 256, 256, 1024, 1024 };
    int Nsz[14] = { 256, 256, 256, 256, 768, 768, 1024, 256, 256, 256, 1024, 1024, 256, 256 };
    int tcum = 0;
    for (int s = 0; s < 14; s++) {
        pa.src[s] = srcs[s]; pa.dst[s] = dsts[s]; pa.K[s] = Ks[s]; pa.N[s] = Nsz[s];
        pa.tstart[s] = tcum;
        tcum += (Ks[s] >> 5) * (Nsz[s] >> 5);
    }
    pa.tstart[14] = tcum;
    prep_tiled<<<tcum, blk, 0, stream>>>(pa);

    // 1) xnb = LN(LN(features @ in_w + in_b)) — fused epilogue, no ln2b launch
    gemm_mfma<true, true><<<dim3(1024, 1), blk, 0, stream>>>(
        features, in_wT, nullptr, in_b, in_ln_g, in_ln_b, ni_g, ni_b,
        xnb, nullptr, Bb * Nn, 768);

    // 2) k and v projections in one launch
    gemm_mfma<false, false><<<dim3(1024, 2), blk, 0, stream>>>(
        xnb, k_wT, v_wT, nullptr, nullptr, nullptr, nullptr, nullptr,
        kb, vb, Bb * Nn, 256);

    // 3) slots init + first q
    slot_init_q<<<Bb, dim3(512), 0, stream>>>(slot_mu, slot_log_sigma, eps_noise,
                                              slots, qbuf, q_wT, ns_g, ns_b);

    // 4) slot-attention iterations (column-parallel splits)
    for (int it = 0; it < 3; it++) {
        dots_softmax<<<Bb * 4, blk, 0, stream>>>(qbuf, kb, attnb);
        updates_kernel<<<Bb * Hh, dim3(512), 0, stream>>>(attnb, vb, upd);
        gru_mm<<<dim3(Bb, 4), blk, 0, stream>>>(upd, slots, wihT, whhT,
                                                gru_bih, gru_bhh, gxh);
        gate_ffn1<<<dim3(Bb, 4), blk, 0, stream>>>(gxh, slots, slots2, fw1T,
                                                   ffn_ln_g, ffn_ln_b, ffn_b1, h1b);
        ffn2_mm<<<dim3(Bb, 4), blk, 0, stream>>>(h1b, slots2, slots, fw2T, ffn_b2);
        if (it < 2)
            ln_q<<<Bb, dim3(512), 0, stream>>>(slots, qbuf, q_wT, ns_g, ns_b);
    }

    // 5) selection + masked x
    select_kernel<<<Bb, blk, 0, stream>>>(slots, sel_w1, sel_b1, sel_w2, sel_b2, dec, xb);

    // 6) GAT layers, phase-split kernels
    for (int l = 0; l < 2; l++) {
        const ushort* gWT = l ? gW1T : gW0T;
        const ushort* g1T = l ? gf1bT : gf1aT;
        const ushort* g2T = l ? gf2bT : gf2aT;
        gat_attn<<<Bb, blk, 0, stream>>>(xb, dec, gWT, gat_a + l * 512,
            gat_ln_g + l * 256, gat_ln_b + l * 256,
            gat_fln_g + l * 256, gat_fln_b + l * 256, yF, ylnb);
        gat_ffn1<<<dim3(Bb, 4), blk, 0, stream>>>(ylnb, g1T, gat_fb1 + l * 1024, gh1);
        gat_ffn2<<<dim3(Bb, 4), blk, 0, stream>>>(gh1, yF, g2T, gat_fb2 + l * 256,
            l ? (float*)d_out : xb);
    }
}